// Round 4
// baseline (147.769 us; speedup 1.0000x reference)
//
#include <hip/hip_runtime.h>

typedef unsigned int uint;
typedef unsigned short ushort_t;

typedef __attribute__((ext_vector_type(8))) short bf16x8;
typedef __attribute__((ext_vector_type(4))) float f32x4;

#define E_CNT 496

__device__ __forceinline__ ushort_t f32_to_bf16_rn(float x) {
    uint u = __float_as_uint(x);
    u = (u + 0x7fffu + ((u >> 16) & 1u)) >> 16;
    return (ushort_t)u;
}
__device__ __forceinline__ uint pack2_bf16(float lo, float hi) {
    return (uint)f32_to_bf16_rn(lo) | ((uint)f32_to_bf16_rn(hi) << 16);
}

// ---------------- prep: W1 -> bf16 image, W2 -> bf16 LDS image, edge decode ----
// blocks 0..31: W1 image [2 halves][256 h][128 d] bf16 (plain layout)
// blocks 32..43: W2 image [96][264] bf16 (k-contiguous, padded rows)
// block 44: edge decode
__global__ __launch_bounds__(256) void prep_kernel(
    const int* __restrict__ sf, const int* __restrict__ st,
    const float* __restrict__ W1, const float* __restrict__ W2,
    int* __restrict__ ef, int* __restrict__ et,
    ushort_t* __restrict__ w1img, ushort_t* __restrict__ w2img) {
    const int tid = threadIdx.x;
    const int blk = blockIdx.x;
    if (blk < 32) {
        int gid = blk * 256 + tid;     // [0, 8192)
        int half = gid >> 12;
        int rem = gid & 4095;
        int h = rem >> 4;
        int c = rem & 15;
        const float* src = W1 + h * 256 + half * 128 + c * 8;
        float4 v0 = *(const float4*)src;
        float4 v1 = *(const float4*)(src + 4);
        uint4 o;
        o.x = pack2_bf16(v0.x, v0.y);
        o.y = pack2_bf16(v0.z, v0.w);
        o.z = pack2_bf16(v1.x, v1.y);
        o.w = pack2_bf16(v1.z, v1.w);
        *(uint4*)(w1img + half * 32768 + h * 128 + c * 8) = o;
    } else if (blk < 44) {
        int gid = (blk - 32) * 256 + tid;  // [0, 3072)
        int n = gid >> 5;
        int c = gid & 31;
        const float* src = W2 + n * 256 + c * 8;
        float4 v0 = *(const float4*)src;
        float4 v1 = *(const float4*)(src + 4);
        uint4 o;
        o.x = pack2_bf16(v0.x, v0.y);
        o.y = pack2_bf16(v0.z, v0.w);
        o.z = pack2_bf16(v1.x, v1.y);
        o.w = pack2_bf16(v1.z, v1.w);
        *(uint4*)(w2img + n * 264 + c * 8) = o;
    } else {
        bool f64 = true, t64 = true;
        #pragma unroll
        for (int i = 0; i < 16; ++i) {
            if (sf[2 * i + 1] != 0) f64 = false;
            if (st[2 * i + 1] != 0) t64 = false;
        }
        for (int j = tid; j < E_CNT; j += 256) {
            ef[j] = f64 ? sf[2 * j] : sf[j];
            et[j] = t64 ? st[2 * j] : st[j];
        }
    }
}

// ---------------- X staging via MFMA (no LDS; w1img read from L2) ------
// grid = 128 M-tiles x 2 halves; block = 256 thr = 4 waves; wave owns 16 rows.
__global__ __launch_bounds__(256) void x_kernel(
    const float* __restrict__ hidden, const ushort_t* __restrict__ w1img,
    const float* __restrict__ b1, ushort_t* __restrict__ Xout) {
    const int tid = threadIdx.x;
    const int half = blockIdx.x & 1;
    const int mblk = blockIdx.x >> 1;

    const int ln = tid & 63;
    const int waveId = tid >> 6;
    const int quad = ln >> 4;
    const int l16 = ln & 15;
    const int row0 = mblk * 64 + waveId * 16;

    // A-frags from global f32 (held in regs, reused over all 16 n-tiles)
    union { uint u[4]; bf16x8 v; } af[4];
    const float* arow = hidden + (row0 + l16) * 128 + quad * 8;
    #pragma unroll
    for (int kk = 0; kk < 4; ++kk) {
        float4 v0 = *(const float4*)(arow + kk * 32);
        float4 v1 = *(const float4*)(arow + kk * 32 + 4);
        af[kk].u[0] = pack2_bf16(v0.x, v0.y);
        af[kk].u[1] = pack2_bf16(v0.z, v0.w);
        af[kk].u[2] = pack2_bf16(v1.x, v1.y);
        af[kk].u[3] = pack2_bf16(v1.z, v1.w);
    }

    const ushort_t* wb = w1img + half * 32768;
    ushort_t* xbase = Xout + half * (8192 * 256);
    #pragma unroll 4
    for (int nt = 0; nt < 16; ++nt) {
        const int h = nt * 16 + l16;
        const ushort_t* wrow = wb + h * 128 + quad * 8;
        bf16x8 bf0 = *(const bf16x8*)(wrow + 0 * 32);
        bf16x8 bf1 = *(const bf16x8*)(wrow + 1 * 32);
        bf16x8 bf2 = *(const bf16x8*)(wrow + 2 * 32);
        bf16x8 bf3 = *(const bf16x8*)(wrow + 3 * 32);
        f32x4 acc = (f32x4){0.f, 0.f, 0.f, 0.f};
        acc = __builtin_amdgcn_mfma_f32_16x16x32_bf16(af[0].v, bf0, acc, 0, 0, 0);
        acc = __builtin_amdgcn_mfma_f32_16x16x32_bf16(af[1].v, bf1, acc, 0, 0, 0);
        acc = __builtin_amdgcn_mfma_f32_16x16x32_bf16(af[2].v, bf2, acc, 0, 0, 0);
        acc = __builtin_amdgcn_mfma_f32_16x16x32_bf16(af[3].v, bf3, acc, 0, 0, 0);
        const float bh = 0.5f * b1[h];
        #pragma unroll
        for (int r = 0; r < 4; ++r) {
            const int row = row0 + quad * 4 + r;
            xbase[row * 256 + h] = f32_to_bf16_rn(acc[r] + bh);
        }
    }
}

// ---------------- fused GEMM2 (MFMA) + payoff ----------------
// block = 512 thr = 8 waves; 128 pairs/block; XCD-swizzled block ids;
// pipelined X gathers (2-kk chunks, depth 1); 1 barrier in epilogue.
#define PAIR_STRIDE 100
#define R_OFF 800
#define WAVE_PF 1600

__global__ __launch_bounds__(512, 4) void gemm_payoff_kernel(
    const ushort_t* __restrict__ X1, const ushort_t* __restrict__ X2,
    const int* __restrict__ ef, const int* __restrict__ et,
    const ushort_t* __restrict__ w2img, const float* __restrict__ b2,
    float* __restrict__ out) {

    __shared__ __align__(16) unsigned char smem[51200];
    ushort_t* w2s = (ushort_t*)smem;  // phase 1: W2 bf16 [96][264] = 50688 B
    float* pf = (float*)smem;         // phase 2: per-wave 1600 floats

    const int tid = threadIdx.x;

    // stage pre-converted W2 image: 3168 x 16B linear copy
    {
        const uint4* src = (const uint4*)w2img;
        uint4* dst = (uint4*)smem;
        #pragma unroll
        for (int j = 0; j < 7; ++j) {
            int idx = tid + j * 512;
            if (idx < 3168) dst[idx] = src[idx];
        }
    }

    const int ln = tid & 63;
    const int waveId = tid >> 6;
    const int quad = ln >> 4;
    const int l16 = ln & 15;
    const int pl = l16 & 7;
    const int s = l16 >> 3;

    // XCD swizzle: 992 = 8 * 124; XCD x gets logical blocks [124x, 124(x+1))
    const int bx = blockIdx.x;
    const int lb = (bx & 7) * 124 + (bx >> 3);

    const int pairBase = lb * 128 + waveId * 16;
    const ushort_t* px1[2];
    const ushort_t* px2[2];
    #pragma unroll
    for (int mt = 0; mt < 2; ++mt) {
        int pair = pairBase + mt * 8 + pl;
        int b = pair / E_CNT;
        int e = pair - b * E_CNT;
        int f = ef[e];
        int t = et[e];
        int n1 = s ? t : f;
        int n2 = s ? f : t;
        px1[mt] = X1 + ((b * 32 + n1) * 256 + quad * 8);
        px2[mt] = X2 + ((b * 32 + n2) * 256 + quad * 8);
    }

    f32x4 acc[2][6];
    #pragma unroll
    for (int mt = 0; mt < 2; ++mt)
        #pragma unroll
        for (int tt = 0; tt < 6; ++tt) acc[mt][tt] = (f32x4){0.f, 0.f, 0.f, 0.f};

    uint4 GA1[2][2], GA2[2][2], GB1[2][2], GB2[2][2];

    auto loadC = [&](uint4 G1[2][2], uint4 G2[2][2], int koff) {
        #pragma unroll
        for (int mt = 0; mt < 2; ++mt)
            #pragma unroll
            for (int k2 = 0; k2 < 2; ++k2) {
                G1[mt][k2] = *(const uint4*)(px1[mt] + (koff + k2) * 32);
                G2[mt][k2] = *(const uint4*)(px2[mt] + (koff + k2) * 32);
            }
    };
    auto computeC = [&](uint4 G1[2][2], uint4 G2[2][2], int koff) {
        #pragma unroll
        for (int k2 = 0; k2 < 2; ++k2) {
            const int kk = koff + k2;
            union { uint u[4]; bf16x8 v; } af[2];
            #pragma unroll
            for (int mt = 0; mt < 2; ++mt) {
                uint ua[4] = {G1[mt][k2].x, G1[mt][k2].y, G1[mt][k2].z, G1[mt][k2].w};
                uint ub[4] = {G2[mt][k2].x, G2[mt][k2].y, G2[mt][k2].z, G2[mt][k2].w};
                #pragma unroll
                for (int w = 0; w < 4; ++w) {
                    float lo = __uint_as_float(ua[w] << 16) + __uint_as_float(ub[w] << 16);
                    float hi = __uint_as_float(ua[w] & 0xffff0000u) + __uint_as_float(ub[w] & 0xffff0000u);
                    lo = fmaxf(lo, 0.f);
                    hi = fmaxf(hi, 0.f);
                    af[mt].u[w] = (__float_as_uint(lo) >> 16) | (__float_as_uint(hi) & 0xffff0000u);
                }
            }
            #pragma unroll
            for (int tt = 0; tt < 6; ++tt) {
                bf16x8 bf = *(const bf16x8*)&w2s[(tt * 16 + l16) * 264 + kk * 32 + quad * 8];
                acc[0][tt] = __builtin_amdgcn_mfma_f32_16x16x32_bf16(af[0].v, bf, acc[0][tt], 0, 0, 0);
                acc[1][tt] = __builtin_amdgcn_mfma_f32_16x16x32_bf16(af[1].v, bf, acc[1][tt], 0, 0, 0);
            }
        }
    };

    loadC(GA1, GA2, 0);   // kk 0-1 in flight
    loadC(GB1, GB2, 2);   // kk 2-3 in flight
    __syncthreads();      // w2s staged
    computeC(GA1, GA2, 0);
    loadC(GA1, GA2, 4);   // kk 4-5
    computeC(GB1, GB2, 2);
    loadC(GB1, GB2, 6);   // kk 6-7
    computeC(GA1, GA2, 4);
    computeC(GB1, GB2, 6);

    float b2v[6];
    #pragma unroll
    for (int tt = 0; tt < 6; ++tt) b2v[tt] = b2[tt * 16 + l16];

    __syncthreads();  // all waves done reading w2s; LDS repurposed (per-wave regions)

    float* wbase = pf + waveId * WAVE_PF;
    #pragma unroll
    for (int mt = 0; mt < 2; ++mt) {
        // dump p (+b2) into payoff layout (per-wave region; in-wave LDS ordering
        // makes dump->read and payoff->next-dump safe without barriers)
        #pragma unroll
        for (int tt = 0; tt < 6; ++tt) {
            const int n = tt * 16 + l16;
            const int rr = n / 24;
            const int rem = n - rr * 24;
            const int c01 = (rem >= 12) ? 1 : 0;
            const int a = rem - c01 * 12;
            #pragma unroll
            for (int r = 0; r < 4; ++r) {
                const int row = quad * 4 + r;
                const int s_ = row >> 3;
                const int pl_ = row & 7;
                const int k8 = (s_ ? 4 : 0) + rr;
                const int toL = (c01 == s_) ? 1 : 0;
                wbase[(toL ? 0 : R_OFF) + pl_ * PAIR_STRIDE + a * 8 + k8] = acc[mt][tt][r] + b2v[tt];
            }
        }

        // payoff: out[i][j] = 0.5 * sum_k8 L[i][k8]*R[j][k8]
        #pragma unroll
        for (int it = 0; it < 2; ++it) {
            int task = it * 64 + ln;
            if (task < 96) {
                int pp = task / 12;
                int i = task - pp * 12;
                const float* Lp = wbase + pp * PAIR_STRIDE + i * 8;
                float4 l0 = *(const float4*)&Lp[0];
                float4 l1 = *(const float4*)&Lp[4];
                float od[12];
                #pragma unroll
                for (int jj = 0; jj < 12; ++jj) {
                    const float* Rp = wbase + R_OFF + pp * PAIR_STRIDE + jj * 8;
                    float4 r0 = *(const float4*)&Rp[0];
                    float4 r1 = *(const float4*)&Rp[4];
                    float d = l0.x * r0.x + l0.y * r0.y + l0.z * r0.z + l0.w * r0.w
                            + l1.x * r1.x + l1.y * r1.y + l1.z * r1.z + l1.w * r1.w;
                    od[jj] = 0.5f * d;
                }
                int outBase = (pairBase + mt * 8 + pp) * 144 + i * 12;
                *(float4*)&out[outBase + 0] = make_float4(od[0], od[1], od[2], od[3]);
                *(float4*)&out[outBase + 4] = make_float4(od[4], od[5], od[6], od[7]);
                *(float4*)&out[outBase + 8] = make_float4(od[8], od[9], od[10], od[11]);
            }
        }
    }
}

extern "C" void kernel_launch(void* const* d_in, const int* in_sizes, int n_in,
                              void* d_out, int out_size, void* d_ws, size_t ws_size,
                              hipStream_t stream) {
    const float* hidden = (const float*)d_in[0];
    const float* W1 = (const float*)d_in[1];
    const float* b1 = (const float*)d_in[2];
    const float* W2 = (const float*)d_in[3];
    const float* b2 = (const float*)d_in[4];
    const int* e_f = (const int*)d_in[5];
    const int* e_t = (const int*)d_in[6];
    float* out = (float*)d_out;

    char* ws = (char*)d_ws;
    int* ef = (int*)ws;                          // @0      (2 KB)
    int* et = (int*)(ws + 4096);                 // @4K     (2 KB)
    ushort_t* w1img = (ushort_t*)(ws + 8192);    // @8K     (128 KB)
    ushort_t* w2img = (ushort_t*)(ws + 139264);  // @136K   (~50 KB)
    ushort_t* X = (ushort_t*)(ws + 190464);      // X1 then X2, 4 MB each

    prep_kernel<<<45, 256, 0, stream>>>(e_f, e_t, W1, W2, ef, et, w1img, w2img);
    x_kernel<<<256, 256, 0, stream>>>(hidden, w1img, b1, X);
    gemm_payoff_kernel<<<992, 512, 0, stream>>>(X, X + 8192 * 256, ef, et, w2img, b2, out);
}

// Round 5
// 140.305 us; speedup vs baseline: 1.0532x; 1.0532x over previous
//
#include <hip/hip_runtime.h>

typedef unsigned int uint;
typedef unsigned short ushort_t;

typedef __attribute__((ext_vector_type(8))) short bf16x8;
typedef __attribute__((ext_vector_type(4))) float f32x4;

#define E_CNT 496

__device__ __forceinline__ ushort_t f32_to_bf16_rn(float x) {
    uint u = __float_as_uint(x);
    u = (u + 0x7fffu + ((u >> 16) & 1u)) >> 16;
    return (ushort_t)u;
}
__device__ __forceinline__ uint pack2_bf16(float lo, float hi) {
    return (uint)f32_to_bf16_rn(lo) | ((uint)f32_to_bf16_rn(hi) << 16);
}

// ---------------- X staging via MFMA; W1 converted f32->bf16 inline ------
// grid = 128 M-tiles x 2 halves; block = 256 thr = 4 waves; wave owns 16 rows.
__global__ __launch_bounds__(256) void x_kernel(
    const float* __restrict__ hidden, const float* __restrict__ W1,
    const float* __restrict__ b1, ushort_t* __restrict__ Xout) {
    __shared__ __align__(16) ushort_t w1s[256 * 128];  // 64 KB swizzled bf16 image

    const int tid = threadIdx.x;
    const int half = blockIdx.x & 1;
    const int mblk = blockIdx.x >> 1;

    // convert W1 half (f32, global) -> swizzled bf16 LDS image
    // thread t: chunk c = t&15 (8 halves), h = it*16 + (t>>4)
    {
        const int c = tid & 15;
        const int h0 = tid >> 4;
        #pragma unroll
        for (int it = 0; it < 16; ++it) {
            const int h = it * 16 + h0;
            const float* src = W1 + h * 256 + half * 128 + c * 8;
            float4 v0 = *(const float4*)src;
            float4 v1 = *(const float4*)(src + 4);
            uint4 o;
            o.x = pack2_bf16(v0.x, v0.y);
            o.y = pack2_bf16(v0.z, v0.w);
            o.z = pack2_bf16(v1.x, v1.y);
            o.w = pack2_bf16(v1.z, v1.w);
            *(uint4*)&w1s[h * 128 + ((c ^ (h & 7)) << 3)] = o;
        }
    }

    const int ln = tid & 63;
    const int waveId = tid >> 6;
    const int quad = ln >> 4;
    const int l16 = ln & 15;
    const int row0 = mblk * 64 + waveId * 16;

    // A-frags from global f32 (held in regs, reused over all 16 n-tiles)
    union { uint u[4]; bf16x8 v; } af[4];
    const float* arow = hidden + (row0 + l16) * 128 + quad * 8;
    #pragma unroll
    for (int kk = 0; kk < 4; ++kk) {
        float4 v0 = *(const float4*)(arow + kk * 32);
        float4 v1 = *(const float4*)(arow + kk * 32 + 4);
        af[kk].u[0] = pack2_bf16(v0.x, v0.y);
        af[kk].u[1] = pack2_bf16(v0.z, v0.w);
        af[kk].u[2] = pack2_bf16(v1.x, v1.y);
        af[kk].u[3] = pack2_bf16(v1.z, v1.w);
    }
    // preload b1 values for this lane's 16 h's
    float bh[16];
    #pragma unroll
    for (int nt = 0; nt < 16; ++nt) bh[nt] = 0.5f * b1[nt * 16 + l16];

    __syncthreads();

    ushort_t* xbase = Xout + half * (8192 * 256);
    #pragma unroll 4
    for (int nt = 0; nt < 16; ++nt) {
        const int h = nt * 16 + l16;
        f32x4 acc = (f32x4){0.f, 0.f, 0.f, 0.f};
        #pragma unroll
        for (int kk = 0; kk < 4; ++kk) {
            const int c_log = kk * 4 + quad;
            bf16x8 bf = *(const bf16x8*)&w1s[h * 128 + ((c_log ^ (h & 7)) << 3)];
            acc = __builtin_amdgcn_mfma_f32_16x16x32_bf16(af[kk].v, bf, acc, 0, 0, 0);
        }
        #pragma unroll
        for (int r = 0; r < 4; ++r) {
            const int row = row0 + quad * 4 + r;
            xbase[row * 256 + h] = f32_to_bf16_rn(acc[r] + bh[nt]);
        }
    }
}

// ---------------- fused GEMM2 (MFMA) + payoff ----------------
// block = 512 thr = 8 waves; 128 pairs/block; XCD-swizzled block ids;
// double-buffered 1-kk pipeline (8 uint4 in flight); W2 conv + edge decode inline.
#define PAIR_STRIDE 100
#define R_OFF 800
#define WAVE_PF 1600

__global__ __launch_bounds__(512, 4) void gemm_payoff_kernel(
    const ushort_t* __restrict__ X1, const ushort_t* __restrict__ X2,
    const int* __restrict__ e_f, const int* __restrict__ e_t,
    const float* __restrict__ W2, const float* __restrict__ b2,
    float* __restrict__ out) {

    __shared__ __align__(16) unsigned char smem[51200];
    ushort_t* w2s = (ushort_t*)smem;  // phase 1: W2 bf16 [96][264] = 50688 B
    float* pf = (float*)smem;         // phase 2: per-wave 1600 floats

    const int tid = threadIdx.x;

    // stage W2 (f32 global) -> bf16 LDS [96][264]
    #pragma unroll
    for (int j = 0; j < 12; ++j) {
        int idx4 = tid + j * 512;  // 0..6143
        int n = idx4 >> 6;
        int k = (idx4 & 63) << 2;
        float4 v = *(const float4*)&W2[n * 256 + k];
        uint2 o;
        o.x = pack2_bf16(v.x, v.y);
        o.y = pack2_bf16(v.z, v.w);
        *(uint2*)&w2s[n * 264 + k] = o;
    }

    const int ln = tid & 63;
    const int waveId = tid >> 6;
    const int quad = ln >> 4;
    const int l16 = ln & 15;
    const int pl = l16 & 7;
    const int s = l16 >> 3;

    // XCD swizzle: 992 = 8 * 124
    const int bx = blockIdx.x;
    const int lb = (bx & 7) * 124 + (bx >> 3);

    // edge dtype detect (uniform -> scalar loads)
    bool f64 = true, t64 = true;
    #pragma unroll
    for (int i = 0; i < 16; ++i) {
        if (e_f[2 * i + 1] != 0) f64 = false;
        if (e_t[2 * i + 1] != 0) t64 = false;
    }

    const int pairBase = lb * 128 + waveId * 16;
    const ushort_t* px1[2];
    const ushort_t* px2[2];
    #pragma unroll
    for (int mt = 0; mt < 2; ++mt) {
        int pair = pairBase + mt * 8 + pl;
        int b = pair / E_CNT;
        int e = pair - b * E_CNT;
        int f = f64 ? e_f[2 * e] : e_f[e];
        int t = t64 ? e_t[2 * e] : e_t[e];
        int n1 = s ? t : f;
        int n2 = s ? f : t;
        px1[mt] = X1 + ((b * 32 + n1) * 256 + quad * 8);
        px2[mt] = X2 + ((b * 32 + n2) * 256 + quad * 8);
    }

    f32x4 acc[2][6];
    #pragma unroll
    for (int mt = 0; mt < 2; ++mt)
        #pragma unroll
        for (int tt = 0; tt < 6; ++tt) acc[mt][tt] = (f32x4){0.f, 0.f, 0.f, 0.f};

    uint4 G1[2][2], G2[2][2];  // [buf][mt]

    #pragma unroll
    for (int mt = 0; mt < 2; ++mt) {
        G1[0][mt] = *(const uint4*)(px1[mt] + 0 * 32);
        G2[0][mt] = *(const uint4*)(px2[mt] + 0 * 32);
        G1[1][mt] = *(const uint4*)(px1[mt] + 1 * 32);
        G2[1][mt] = *(const uint4*)(px2[mt] + 1 * 32);
    }

    __syncthreads();  // w2s staged

    #pragma unroll
    for (int kk = 0; kk < 8; ++kk) {
        const int buf = kk & 1;
        // consume G[buf] -> A-frags
        union { uint u[4]; bf16x8 v; } af[2];
        #pragma unroll
        for (int mt = 0; mt < 2; ++mt) {
            uint ua[4] = {G1[buf][mt].x, G1[buf][mt].y, G1[buf][mt].z, G1[buf][mt].w};
            uint ub[4] = {G2[buf][mt].x, G2[buf][mt].y, G2[buf][mt].z, G2[buf][mt].w};
            #pragma unroll
            for (int w = 0; w < 4; ++w) {
                float lo = __uint_as_float(ua[w] << 16) + __uint_as_float(ub[w] << 16);
                float hi = __uint_as_float(ua[w] & 0xffff0000u) + __uint_as_float(ub[w] & 0xffff0000u);
                lo = fmaxf(lo, 0.f);
                hi = fmaxf(hi, 0.f);
                af[mt].u[w] = (__float_as_uint(lo) >> 16) | (__float_as_uint(hi) & 0xffff0000u);
            }
        }
        // prefetch kk+2 into the just-freed buffer
        if (kk < 6) {
            #pragma unroll
            for (int mt = 0; mt < 2; ++mt) {
                G1[buf][mt] = *(const uint4*)(px1[mt] + (kk + 2) * 32);
                G2[buf][mt] = *(const uint4*)(px2[mt] + (kk + 2) * 32);
            }
        }
        #pragma unroll
        for (int tt = 0; tt < 6; ++tt) {
            bf16x8 bf = *(const bf16x8*)&w2s[(tt * 16 + l16) * 264 + kk * 32 + quad * 8];
            acc[0][tt] = __builtin_amdgcn_mfma_f32_16x16x32_bf16(af[0].v, bf, acc[0][tt], 0, 0, 0);
            acc[1][tt] = __builtin_amdgcn_mfma_f32_16x16x32_bf16(af[1].v, bf, acc[1][tt], 0, 0, 0);
        }
    }

    float b2v[6];
    #pragma unroll
    for (int tt = 0; tt < 6; ++tt) b2v[tt] = b2[tt * 16 + l16];

    __syncthreads();  // all waves done reading w2s; LDS repurposed (per-wave regions)

    float* wbase = pf + waveId * WAVE_PF;
    #pragma unroll
    for (int mt = 0; mt < 2; ++mt) {
        // dump p (+b2) into payoff layout (per-wave region; in-wave LDS ordering)
        #pragma unroll
        for (int tt = 0; tt < 6; ++tt) {
            const int n = tt * 16 + l16;
            const int rr = n / 24;
            const int rem = n - rr * 24;
            const int c01 = (rem >= 12) ? 1 : 0;
            const int a = rem - c01 * 12;
            #pragma unroll
            for (int r = 0; r < 4; ++r) {
                const int row = quad * 4 + r;
                const int s_ = row >> 3;
                const int pl_ = row & 7;
                const int k8 = (s_ ? 4 : 0) + rr;
                const int toL = (c01 == s_) ? 1 : 0;
                wbase[(toL ? 0 : R_OFF) + pl_ * PAIR_STRIDE + a * 8 + k8] = acc[mt][tt][r] + b2v[tt];
            }
        }

        // payoff: out[i][j] = 0.5 * sum_k8 L[i][k8]*R[j][k8]
        #pragma unroll
        for (int it = 0; it < 2; ++it) {
            int task = it * 64 + ln;
            if (task < 96) {
                int pp = task / 12;
                int i = task - pp * 12;
                const float* Lp = wbase + pp * PAIR_STRIDE + i * 8;
                float4 l0 = *(const float4*)&Lp[0];
                float4 l1 = *(const float4*)&Lp[4];
                float od[12];
                #pragma unroll
                for (int jj = 0; jj < 12; ++jj) {
                    const float* Rp = wbase + R_OFF + pp * PAIR_STRIDE + jj * 8;
                    float4 r0 = *(const float4*)&Rp[0];
                    float4 r1 = *(const float4*)&Rp[4];
                    float d = l0.x * r0.x + l0.y * r0.y + l0.z * r0.z + l0.w * r0.w
                            + l1.x * r1.x + l1.y * r1.y + l1.z * r1.z + l1.w * r1.w;
                    od[jj] = 0.5f * d;
                }
                int outBase = (pairBase + mt * 8 + pp) * 144 + i * 12;
                *(float4*)&out[outBase + 0] = make_float4(od[0], od[1], od[2], od[3]);
                *(float4*)&out[outBase + 4] = make_float4(od[4], od[5], od[6], od[7]);
                *(float4*)&out[outBase + 8] = make_float4(od[8], od[9], od[10], od[11]);
            }
        }
    }
}

extern "C" void kernel_launch(void* const* d_in, const int* in_sizes, int n_in,
                              void* d_out, int out_size, void* d_ws, size_t ws_size,
                              hipStream_t stream) {
    const float* hidden = (const float*)d_in[0];
    const float* W1 = (const float*)d_in[1];
    const float* b1 = (const float*)d_in[2];
    const float* W2 = (const float*)d_in[3];
    const float* b2 = (const float*)d_in[4];
    const int* e_f = (const int*)d_in[5];
    const int* e_t = (const int*)d_in[6];
    float* out = (float*)d_out;

    char* ws = (char*)d_ws;
    ushort_t* X = (ushort_t*)ws;   // X1 then X2, 4 MB each

    x_kernel<<<256, 256, 0, stream>>>(hidden, W1, b1, X);
    gemm_payoff_kernel<<<992, 512, 0, stream>>>(X, X + 8192 * 256, e_f, e_t, W2, b2, out);
}

// Round 6
// 137.666 us; speedup vs baseline: 1.0734x; 1.0192x over previous
//
#include <hip/hip_runtime.h>

typedef unsigned int uint;
typedef unsigned short ushort_t;
typedef _Float16 f16;

typedef __attribute__((ext_vector_type(8))) _Float16 f16x8;
typedef __attribute__((ext_vector_type(2))) _Float16 f16x2;
typedef __attribute__((ext_vector_type(4))) float f32x4;

#define E_CNT 496

__device__ __forceinline__ uint pack2_f16(float lo, float hi) {
    union { f16x2 h; uint u; } r;
    r.h[0] = (_Float16)lo;
    r.h[1] = (_Float16)hi;
    return r.u;
}

// ---------------- X staging via MFMA; W1 converted f32->f16 inline ------
// grid = 128 M-tiles x 2 halves; block = 256 thr = 4 waves; wave owns 16 rows.
__global__ __launch_bounds__(256) void x_kernel(
    const float* __restrict__ hidden, const float* __restrict__ W1,
    const float* __restrict__ b1, f16* __restrict__ Xout) {
    __shared__ __align__(16) f16 w1s[256 * 128];  // 64 KB swizzled f16 image

    const int tid = threadIdx.x;
    const int half = blockIdx.x & 1;
    const int mblk = blockIdx.x >> 1;

    // convert W1 half (f32, global) -> swizzled f16 LDS image
    {
        const int c = tid & 15;
        const int h0 = tid >> 4;
        #pragma unroll
        for (int it = 0; it < 16; ++it) {
            const int h = it * 16 + h0;
            const float* src = W1 + h * 256 + half * 128 + c * 8;
            float4 v0 = *(const float4*)src;
            float4 v1 = *(const float4*)(src + 4);
            uint4 o;
            o.x = pack2_f16(v0.x, v0.y);
            o.y = pack2_f16(v0.z, v0.w);
            o.z = pack2_f16(v1.x, v1.y);
            o.w = pack2_f16(v1.z, v1.w);
            *(uint4*)&w1s[h * 128 + ((c ^ (h & 7)) << 3)] = o;
        }
    }

    const int ln = tid & 63;
    const int waveId = tid >> 6;
    const int quad = ln >> 4;
    const int l16 = ln & 15;
    const int row0 = mblk * 64 + waveId * 16;

    // A-frags from global f32 (held in regs, reused over all 16 n-tiles)
    union { uint u[4]; f16x8 v; } af[4];
    const float* arow = hidden + (row0 + l16) * 128 + quad * 8;
    #pragma unroll
    for (int kk = 0; kk < 4; ++kk) {
        float4 v0 = *(const float4*)(arow + kk * 32);
        float4 v1 = *(const float4*)(arow + kk * 32 + 4);
        af[kk].u[0] = pack2_f16(v0.x, v0.y);
        af[kk].u[1] = pack2_f16(v0.z, v0.w);
        af[kk].u[2] = pack2_f16(v1.x, v1.y);
        af[kk].u[3] = pack2_f16(v1.z, v1.w);
    }
    // preload b1 values for this lane's 16 h's
    float bh[16];
    #pragma unroll
    for (int nt = 0; nt < 16; ++nt) bh[nt] = 0.5f * b1[nt * 16 + l16];

    __syncthreads();

    f16* xbase = Xout + half * (8192 * 256);
    #pragma unroll 4
    for (int nt = 0; nt < 16; ++nt) {
        const int h = nt * 16 + l16;
        f32x4 acc = (f32x4){0.f, 0.f, 0.f, 0.f};
        #pragma unroll
        for (int kk = 0; kk < 4; ++kk) {
            const int c_log = kk * 4 + quad;
            f16x8 bf = *(const f16x8*)&w1s[h * 128 + ((c_log ^ (h & 7)) << 3)];
            acc = __builtin_amdgcn_mfma_f32_16x16x32_f16(af[kk].v, bf, acc, 0, 0, 0);
        }
        #pragma unroll
        for (int r = 0; r < 4; ++r) {
            const int row = row0 + quad * 4 + r;
            xbase[row * 256 + h] = (_Float16)(acc[r] + bh[nt]);
        }
    }
}

// ---------------- fused GEMM2 (MFMA, fp16) + payoff ----------------
// block = 512 thr = 8 waves; 128 pairs/block; XCD-swizzled block ids;
// double-buffered 1-kk pipeline; relu(x1+x2) via v_pk_add_f16/v_pk_max_f16.
#define PAIR_STRIDE 100
#define R_OFF 800
#define WAVE_PF 1600

__global__ __launch_bounds__(512, 4) void gemm_payoff_kernel(
    const f16* __restrict__ X1, const f16* __restrict__ X2,
    const int* __restrict__ e_f, const int* __restrict__ e_t,
    const float* __restrict__ W2, const float* __restrict__ b2,
    float* __restrict__ out) {

    __shared__ __align__(16) unsigned char smem[51200];
    f16* w2s = (f16*)smem;    // phase 1: W2 f16 [96][264] = 50688 B
    float* pf = (float*)smem; // phase 2: per-wave 1600 floats

    const int tid = threadIdx.x;

    // stage W2 (f32 global) -> f16 LDS [96][264]
    #pragma unroll
    for (int j = 0; j < 12; ++j) {
        int idx4 = tid + j * 512;  // 0..6143
        int n = idx4 >> 6;
        int k = (idx4 & 63) << 2;
        float4 v = *(const float4*)&W2[n * 256 + k];
        uint2 o;
        o.x = pack2_f16(v.x, v.y);
        o.y = pack2_f16(v.z, v.w);
        *(uint2*)&w2s[n * 264 + k] = o;
    }

    const int ln = tid & 63;
    const int waveId = tid >> 6;
    const int quad = ln >> 4;
    const int l16 = ln & 15;
    const int pl = l16 & 7;
    const int s = l16 >> 3;

    // XCD swizzle: 992 = 8 * 124
    const int bx = blockIdx.x;
    const int lb = (bx & 7) * 124 + (bx >> 3);

    // edge dtype detect (uniform -> scalar loads)
    bool f64 = true, t64 = true;
    #pragma unroll
    for (int i = 0; i < 16; ++i) {
        if (e_f[2 * i + 1] != 0) f64 = false;
        if (e_t[2 * i + 1] != 0) t64 = false;
    }

    const int pairBase = lb * 128 + waveId * 16;
    const f16* px1[2];
    const f16* px2[2];
    #pragma unroll
    for (int mt = 0; mt < 2; ++mt) {
        int pair = pairBase + mt * 8 + pl;
        int b = pair / E_CNT;
        int e = pair - b * E_CNT;
        int f = f64 ? e_f[2 * e] : e_f[e];
        int t = t64 ? e_t[2 * e] : e_t[e];
        int n1 = s ? t : f;
        int n2 = s ? f : t;
        px1[mt] = X1 + ((b * 32 + n1) * 256 + quad * 8);
        px2[mt] = X2 + ((b * 32 + n2) * 256 + quad * 8);
    }

    f32x4 acc[2][6];
    #pragma unroll
    for (int mt = 0; mt < 2; ++mt)
        #pragma unroll
        for (int tt = 0; tt < 6; ++tt) acc[mt][tt] = (f32x4){0.f, 0.f, 0.f, 0.f};

    typedef union { uint4 q; f16x8 h; } XU;
    XU G1[2][2], G2[2][2];  // [buf][mt]

    #pragma unroll
    for (int mt = 0; mt < 2; ++mt) {
        G1[0][mt].q = *(const uint4*)(px1[mt] + 0 * 32);
        G2[0][mt].q = *(const uint4*)(px2[mt] + 0 * 32);
        G1[1][mt].q = *(const uint4*)(px1[mt] + 1 * 32);
        G2[1][mt].q = *(const uint4*)(px2[mt] + 1 * 32);
    }

    const f16x8 zero8 = (f16x8){0, 0, 0, 0, 0, 0, 0, 0};

    __syncthreads();  // w2s staged

    #pragma unroll
    for (int kk = 0; kk < 8; ++kk) {
        const int buf = kk & 1;
        // consume G[buf] -> A-frags: relu(x1+x2) in packed fp16 (2 VALU / dword-pair)
        f16x8 af[2];
        #pragma unroll
        for (int mt = 0; mt < 2; ++mt) {
            f16x8 sum = G1[buf][mt].h + G2[buf][mt].h;
            af[mt] = __builtin_elementwise_max(sum, zero8);
        }
        // prefetch kk+2 into the just-freed buffer
        if (kk < 6) {
            #pragma unroll
            for (int mt = 0; mt < 2; ++mt) {
                G1[buf][mt].q = *(const uint4*)(px1[mt] + (kk + 2) * 32);
                G2[buf][mt].q = *(const uint4*)(px2[mt] + (kk + 2) * 32);
            }
        }
        #pragma unroll
        for (int tt = 0; tt < 6; ++tt) {
            f16x8 bf = *(const f16x8*)&w2s[(tt * 16 + l16) * 264 + kk * 32 + quad * 8];
            acc[0][tt] = __builtin_amdgcn_mfma_f32_16x16x32_f16(af[0], bf, acc[0][tt], 0, 0, 0);
            acc[1][tt] = __builtin_amdgcn_mfma_f32_16x16x32_f16(af[1], bf, acc[1][tt], 0, 0, 0);
        }
    }

    float b2v[6];
    #pragma unroll
    for (int tt = 0; tt < 6; ++tt) b2v[tt] = b2[tt * 16 + l16];

    __syncthreads();  // all waves done reading w2s; LDS repurposed (per-wave regions)

    float* wbase = pf + waveId * WAVE_PF;
    #pragma unroll
    for (int mt = 0; mt < 2; ++mt) {
        // dump p (+b2) into payoff layout (per-wave region; in-wave LDS ordering)
        #pragma unroll
        for (int tt = 0; tt < 6; ++tt) {
            const int n = tt * 16 + l16;
            const int rr = n / 24;
            const int rem = n - rr * 24;
            const int c01 = (rem >= 12) ? 1 : 0;
            const int a = rem - c01 * 12;
            #pragma unroll
            for (int r = 0; r < 4; ++r) {
                const int row = quad * 4 + r;
                const int s_ = row >> 3;
                const int pl_ = row & 7;
                const int k8 = (s_ ? 4 : 0) + rr;
                const int toL = (c01 == s_) ? 1 : 0;
                wbase[(toL ? 0 : R_OFF) + pl_ * PAIR_STRIDE + a * 8 + k8] = acc[mt][tt][r] + b2v[tt];
            }
        }

        // payoff: out[i][j] = 0.5 * sum_k8 L[i][k8]*R[j][k8]
        #pragma unroll
        for (int it = 0; it < 2; ++it) {
            int task = it * 64 + ln;
            if (task < 96) {
                int pp = task / 12;
                int i = task - pp * 12;
                const float* Lp = wbase + pp * PAIR_STRIDE + i * 8;
                float4 l0 = *(const float4*)&Lp[0];
                float4 l1 = *(const float4*)&Lp[4];
                float od[12];
                #pragma unroll
                for (int jj = 0; jj < 12; ++jj) {
                    const float* Rp = wbase + R_OFF + pp * PAIR_STRIDE + jj * 8;
                    float4 r0 = *(const float4*)&Rp[0];
                    float4 r1 = *(const float4*)&Rp[4];
                    float d = l0.x * r0.x + l0.y * r0.y + l0.z * r0.z + l0.w * r0.w
                            + l1.x * r1.x + l1.y * r1.y + l1.z * r1.z + l1.w * r1.w;
                    od[jj] = 0.5f * d;
                }
                int outBase = (pairBase + mt * 8 + pp) * 144 + i * 12;
                *(float4*)&out[outBase + 0] = make_float4(od[0], od[1], od[2], od[3]);
                *(float4*)&out[outBase + 4] = make_float4(od[4], od[5], od[6], od[7]);
                *(float4*)&out[outBase + 8] = make_float4(od[8], od[9], od[10], od[11]);
            }
        }
    }
}

extern "C" void kernel_launch(void* const* d_in, const int* in_sizes, int n_in,
                              void* d_out, int out_size, void* d_ws, size_t ws_size,
                              hipStream_t stream) {
    const float* hidden = (const float*)d_in[0];
    const float* W1 = (const float*)d_in[1];
    const float* b1 = (const float*)d_in[2];
    const float* W2 = (const float*)d_in[3];
    const float* b2 = (const float*)d_in[4];
    const int* e_f = (const int*)d_in[5];
    const int* e_t = (const int*)d_in[6];
    float* out = (float*)d_out;

    char* ws = (char*)d_ws;
    f16* X = (f16*)ws;   // X1 then X2, 4 MB each

    x_kernel<<<256, 256, 0, stream>>>(hidden, W1, b1, X);
    gemm_payoff_kernel<<<992, 512, 0, stream>>>(X, X + 8192 * 256, e_f, e_t, W2, b2, out);
}